// Round 14
// baseline (190.305 us; speedup 1.0000x reference)
//
#include <hip/hip_runtime.h>

// DeepSets fused kernel for MI355X (gfx950) — round 14.
// r13 FAILED correctness: base+literal LDS addressing broke the XOR swizzle
// (ks<<6 / ct<<5 collide with swizzle bits 4-7 -> carry corrupts the row).
// r14 = r13's structure (128-row tiles, ONE barrier/iter, 160KB LDS) with
// r12's PROVEN full address computation (XOR applied after all in-row terms).

typedef unsigned short u16;
typedef _Float16 f16x8 __attribute__((ext_vector_type(8)));
typedef float f32x4 __attribute__((ext_vector_type(4)));
typedef int i32x4 __attribute__((ext_vector_type(4)));

#define NBLK 256

// ---------------- prep: fp32 weights -> fp16 fragments, zero gsum, warm L3 ---
// Fragment layout (validated r1-r12): lane l, elem j holds W[k=32*ks+8*(l>>4)+j][16*ctg+(l&15)]
// at frag[((ctg*KS+ks)*64 + l)*8 + j]. Used as MFMA *A* operand: D = W^T X^T = (XW)^T.
__global__ void prep_kernel(const float* __restrict__ pw1, const float* __restrict__ pw2,
                            _Float16* __restrict__ w1f, _Float16* __restrict__ w2f,
                            float* __restrict__ gsum,
                            const float* __restrict__ pw3, const float* __restrict__ rw1,
                            const float* __restrict__ rw2, const float* __restrict__ rw3,
                            const float* __restrict__ hw1, const float* __restrict__ hw2,
                            const float* __restrict__ hw3) {
    int idx = blockIdx.x * blockDim.x + threadIdx.x;   // 160*512 = 81920
    if (idx < 256) gsum[idx] = 0.f;
    if (idx < 16384) {  // pw1: 64x256, KS=2
        int j = idx & 7, l = (idx >> 3) & 63, ks = (idx >> 9) & 1, ct = idx >> 10;
        int k = 32 * ks + 8 * (l >> 4) + j;
        int col = 16 * ct + (l & 15);
        w1f[idx] = (_Float16)pw1[k * 256 + col];
    } else {            // pw2: 256x256, KS=8
        int o = idx - 16384;
        int j = o & 7, l = (o >> 3) & 63, ks = (o >> 9) & 7, ct = o >> 12;
        int k = 32 * ks + 8 * (l >> 4) + j;
        int col = 16 * ct + (l & 15);
        w2f[o] = (_Float16)pw2[k * 256 + col];
    }
    // warm rho/head weights into L3 so tail_kernel doesn't stream cold HBM
    float s = 0.f;
    if (idx < 32768) s += pw3[idx];
    if (idx < 32768) s += rw1[idx];
    if (idx < 65536) s += rw2[idx];
    if (idx < 32768) s += rw3[idx];
    if (idx < 36864) s += hw1[idx];
    if (idx < 65536) s += hw2[idx];
    if (idx < 1280)  s += hw3[idx];
    asm volatile("" :: "v"(s));
}

__device__ __forceinline__ void pin_reg(f16x8& v) {
    i32x4 t = __builtin_bit_cast(i32x4, v);
    asm volatile("" : "+v"(t));
    v = __builtin_bit_cast(f16x8, t);
}
__device__ __forceinline__ unsigned pk(float a, float b) {
    return __builtin_bit_cast(unsigned, __builtin_amdgcn_cvt_pkrtz(a, b));
}

// ---------------- fused phi + pool (persistent, 128-row tiles) ---------------
// 8 waves; wave w owns h/out cols [32w, 32w+32). One barrier per 128-row tile.
__global__ __attribute__((amdgpu_flat_work_group_size(512, 512), amdgpu_waves_per_eu(2, 2)))
void phi_kernel(
    const float* __restrict__ x,
    const float* __restrict__ pb1, const float* __restrict__ pb2,
    const _Float16* __restrict__ w1g, const _Float16* __restrict__ w2g,
    float* __restrict__ gsum, int ntiles) {
    __shared__ __align__(16) u16 xs[2][128 * 64];    // 2x16KB, swz ^((row&7)<<4)
    __shared__ __align__(16) u16 h1s[2][128 * 256];  // 2x64KB, swz ^((row&15)<<4)

    const int tid = threadIdx.x;
    const int l = tid & 63;
    const int w = tid >> 6;
    const int fr = l & 15;
    const int fg = l >> 4;
    const int wb = w * 32;

    // ---- preload weight fragments into registers (loop-invariant, pinned)
    f16x8 w1r[2][2];   // [ct][ks]
#pragma unroll
    for (int ct = 0; ct < 2; ++ct)
#pragma unroll
        for (int ks = 0; ks < 2; ++ks) {
            int ctg = 2 * w + ct;
            w1r[ct][ks] = *(const f16x8*)(w1g + (((ctg << 1) + ks) << 9) + (l << 3));
        }
    f16x8 w2r[2][8];   // [ct][ks]
#pragma unroll
    for (int ct = 0; ct < 2; ++ct)
#pragma unroll
        for (int ks = 0; ks < 8; ++ks) {
            int ctg = 2 * w + ct;
            w2r[ct][ks] = *(const f16x8*)(w2g + (((ctg << 3) + ks) << 9) + (l << 3));
        }
#pragma unroll
    for (int ct = 0; ct < 2; ++ct) {
#pragma unroll
        for (int ks = 0; ks < 2; ++ks) pin_reg(w1r[ct][ks]);
#pragma unroll
        for (int ks = 0; ks < 8; ++ks) pin_reg(w2r[ct][ks]);
    }
    f32x4 b1v[2], b2v[2];
#pragma unroll
    for (int ct = 0; ct < 2; ++ct) {
        int c0 = wb + ct * 16 + fg * 4;
        b1v[ct] = *(const f32x4*)(pb1 + c0);
        b2v[ct] = *(const f32x4*)(pb2 + c0);
    }

    float psum[2][4] = {{0.f, 0.f, 0.f, 0.f}, {0.f, 0.f, 0.f, 0.f}};

    const int t0 = blockIdx.x;
    // ---- prologue: stage tile t0 into xs[0] (128x64 fp32 = 2048 float4)
    {
        const float4* xg = (const float4*)(x + (size_t)t0 * 8192);
#pragma unroll
        for (int i = 0; i < 4; ++i) {
            int f4 = tid + i * 512;
            float4 v = xg[f4];
            int row = f4 >> 4, c4 = f4 & 15;
            uint2 o;
            o.x = pk(v.x, v.y);
            o.y = pk(v.z, v.w);
            int byte = (row * 128 + c4 * 8) ^ ((row & 7) << 4);
            *(uint2*)((char*)xs[0] + byte) = o;
        }
    }
    float4 pf[4];
    {
        int tn = (t0 + NBLK < ntiles) ? t0 + NBLK : 0;
        const float4* xg = (const float4*)(x + (size_t)tn * 8192);
#pragma unroll
        for (int i = 0; i < 4; ++i) pf[i] = xg[tid + i * 512];
    }
    __syncthreads();

    int buf = 0, hb = 0;
    for (int t = t0; t < ntiles; t += NBLK) {
        // ---- stage next x tile (consume pf -> xs[buf^1])
#pragma unroll
        for (int i = 0; i < 4; ++i) {
            float4 v = pf[i];
            int f4 = tid + i * 512;
            int row = f4 >> 4, c4 = f4 & 15;
            uint2 o;
            o.x = pk(v.x, v.y);
            o.y = pk(v.z, v.w);
            int byte = (row * 128 + c4 * 8) ^ ((row & 7) << 4);
            *(uint2*)((char*)xs[buf ^ 1] + byte) = o;
        }
        // ---- issue global loads for t+2*NBLK (land during GEMM1/GEMM2)
        {
            int tn = (t + 2 * NBLK < ntiles) ? t + 2 * NBLK : 0;
            const float4* xg = (const float4*)(x + (size_t)tn * 8192);
#pragma unroll
            for (int i = 0; i < 4; ++i) pf[i] = xg[tid + i * 512];
        }

        // ---- GEMM1: h1 = relu(x@pw1+pb1), two rh passes (r12 addressing)
#pragma unroll
        for (int rh = 0; rh < 2; ++rh) {
            f32x4 acc[2][4] = {};
#pragma unroll
            for (int ks = 0; ks < 2; ++ks) {
                f16x8 bd[4];
#pragma unroll
                for (int rt = 0; rt < 4; ++rt) {
                    int row = rh * 64 + (rt << 4) + fr;
                    int byte = ((row << 7) + (ks << 6) + (fg << 4)) ^ ((fr & 7) << 4);
                    bd[rt] = *(const f16x8*)((char*)xs[buf] + byte);
                }
#pragma unroll
                for (int ct = 0; ct < 2; ++ct)
#pragma unroll
                    for (int rt = 0; rt < 4; ++rt)
                        acc[ct][rt] = __builtin_amdgcn_mfma_f32_16x16x32_f16(w1r[ct][ks], bd[rt], acc[ct][rt], 0, 0, 0);
            }
#pragma unroll
            for (int ct = 0; ct < 2; ++ct) {
                int c0 = wb + ct * 16 + fg * 4;
#pragma unroll
                for (int rt = 0; rt < 4; ++rt) {
                    int rown = rh * 64 + (rt << 4) + fr;
                    uint2 o;
                    o.x = pk(fmaxf(acc[ct][rt][0] + b1v[ct][0], 0.f),
                             fmaxf(acc[ct][rt][1] + b1v[ct][1], 0.f));
                    o.y = pk(fmaxf(acc[ct][rt][2] + b1v[ct][2], 0.f),
                             fmaxf(acc[ct][rt][3] + b1v[ct][3], 0.f));
                    int byte = ((rown << 9) + (c0 << 1)) ^ (fr << 4);
                    *(uint2*)((char*)h1s[hb] + byte) = o;
                }
            }
        }
        __syncthreads();   // h1s[hb] complete; xs[buf^1] staged; pf in flight

        // ---- GEMM2: pool relu(h1@pw2+pb2), two rh passes (r12 addressing)
#pragma unroll
        for (int rh = 0; rh < 2; ++rh) {
            f32x4 acc2[2][4] = {};
#pragma unroll
            for (int ks = 0; ks < 8; ++ks) {
                f16x8 bd[4];
#pragma unroll
                for (int rt = 0; rt < 4; ++rt) {
                    int row = rh * 64 + (rt << 4) + fr;
                    int byte = ((row << 9) + (ks << 6) + (fg << 4)) ^ (fr << 4);
                    bd[rt] = *(const f16x8*)((char*)h1s[hb] + byte);
                }
#pragma unroll
                for (int ct = 0; ct < 2; ++ct)
#pragma unroll
                    for (int rt = 0; rt < 4; ++rt)
                        acc2[ct][rt] = __builtin_amdgcn_mfma_f32_16x16x32_f16(w2r[ct][ks], bd[rt], acc2[ct][rt], 0, 0, 0);
            }
#pragma unroll
            for (int ct = 0; ct < 2; ++ct)
#pragma unroll
                for (int r = 0; r < 4; ++r) {
                    float v = 0.f;
#pragma unroll
                    for (int rt = 0; rt < 4; ++rt)
                        v += fmaxf(acc2[ct][rt][r] + b2v[ct][r], 0.f);
                    psum[ct][r] += v;
                }
        }
        buf ^= 1;
        hb ^= 1;
    }

    // ---- final: reduce psum over the 16 fr-lanes, one atomicAdd per col
#pragma unroll
    for (int ct = 0; ct < 2; ++ct)
#pragma unroll
        for (int r = 0; r < 4; ++r) {
            float v = psum[ct][r];
            v += __shfl_xor(v, 1, 64);
            v += __shfl_xor(v, 2, 64);
            v += __shfl_xor(v, 4, 64);
            v += __shfl_xor(v, 8, 64);
            if (fr == 0) atomicAdd(&gsum[wb + ct * 16 + fg * 4 + r], v);
        }
}

// ---------------- tail: split-K parallel rho + head (fp32, 1024 threads) ----
__global__ __launch_bounds__(1024) void tail_kernel(
    const float* __restrict__ gsum, const float* __restrict__ xst,
    const float* __restrict__ pw3, const float* __restrict__ pb3,
    const float* __restrict__ rw1, const float* __restrict__ rb1,
    const float* __restrict__ rw2, const float* __restrict__ rb2,
    const float* __restrict__ rw3, const float* __restrict__ rb3,
    const float* __restrict__ w1, const float* __restrict__ b1,
    const float* __restrict__ w2, const float* __restrict__ b2,
    const float* __restrict__ w3, const float* __restrict__ b3,
    float* __restrict__ out, float nf) {
    __shared__ float fp[128], r1[256], r2[256], tc[144], t1[256], t2[256];
    __shared__ float part[8][256];
    const int t = threadIdx.x;

    {   // fp = nf*pb3 + gsum @ pw3  (256->128, 8-way)
        int j = t & 127, q = t >> 7;
        float s = 0.f;
        for (int i = 32 * q; i < 32 * q + 32; ++i) s += gsum[i] * pw3[i * 128 + j];
        part[q][j] = s;
    }
    __syncthreads();
    if (t < 128) { float s = nf * pb3[t]; for (int q = 0; q < 8; ++q) s += part[q][t]; fp[t] = s; }
    __syncthreads();
    {   // r1 = relu(fp @ rw1 + rb1)  (128->256, 4-way)
        int j = t & 255, q = t >> 8;
        float s = 0.f;
        for (int i = 32 * q; i < 32 * q + 32; ++i) s += fp[i] * rw1[i * 256 + j];
        part[q][j] = s;
    }
    __syncthreads();
    if (t < 256) { float s = rb1[t]; for (int q = 0; q < 4; ++q) s += part[q][t]; r1[t] = fmaxf(s, 0.f); }
    __syncthreads();
    {   // r2 = relu(r1 @ rw2 + rb2)  (256->256, 4-way)
        int j = t & 255, q = t >> 8;
        float s = 0.f;
        for (int i = 64 * q; i < 64 * q + 64; ++i) s += r1[i] * rw2[i * 256 + j];
        part[q][j] = s;
    }
    __syncthreads();
    if (t < 256) { float s = rb2[t]; for (int q = 0; q < 4; ++q) s += part[q][t]; r2[t] = fmaxf(s, 0.f); }
    __syncthreads();
    {   // tc[0:128] = r2 @ rw3 + rb3  (256->128, 8-way)
        int j = t & 127, q = t >> 7;
        float s = 0.f;
        for (int i = 32 * q; i < 32 * q + 32; ++i) s += r2[i] * rw3[i * 128 + j];
        part[q][j] = s;
    }
    __syncthreads();
    if (t < 128) { float s = rb3[t]; for (int q = 0; q < 8; ++q) s += part[q][t]; tc[t] = s; }
    else if (t < 144) tc[t] = xst[t - 128];
    __syncthreads();
    {   // t1 = relu(tc @ w1 + b1)  (144->256, 4-way, 36 each)
        int j = t & 255, q = t >> 8;
        float s = 0.f;
        for (int i = 36 * q; i < 36 * q + 36; ++i) s += tc[i] * w1[i * 256 + j];
        part[q][j] = s;
    }
    __syncthreads();
    if (t < 256) { float s = b1[t]; for (int q = 0; q < 4; ++q) s += part[q][t]; t1[t] = fmaxf(s, 0.f); }
    __syncthreads();
    {   // t2 = relu(t1 @ w2 + b2)  (256->256, 4-way)
        int j = t & 255, q = t >> 8;
        float s = 0.f;
        for (int i = 64 * q; i < 64 * q + 64; ++i) s += t1[i] * w2[i * 256 + j];
        part[q][j] = s;
    }
    __syncthreads();
    if (t < 256) { float s = b2[t]; for (int q = 0; q < 4; ++q) s += part[q][t]; t2[t] = fmaxf(s, 0.f); }
    __syncthreads();
    {   // out = t2 @ w3 + b3  (256->5, 4-way)
        int j = t & 255, q = t >> 8;
        if (j < 5) {
            float s = 0.f;
            for (int i = 64 * q; i < 64 * q + 64; ++i) s += t2[i] * w3[i * 5 + j];
            part[q][j] = s;
        }
    }
    __syncthreads();
    if (t < 5) { float s = b3[t]; for (int q = 0; q < 4; ++q) s += part[q][t]; out[t] = s; }
}

extern "C" void kernel_launch(void* const* d_in, const int* in_sizes, int n_in,
                              void* d_out, int out_size, void* d_ws, size_t ws_size,
                              hipStream_t stream) {
    (void)n_in; (void)out_size; (void)ws_size;
    const float* x   = (const float*)d_in[0];
    const float* xst = (const float*)d_in[1];
    const float* pw1 = (const float*)d_in[2];
    const float* pb1 = (const float*)d_in[3];
    const float* pw2 = (const float*)d_in[4];
    const float* pb2 = (const float*)d_in[5];
    const float* pw3 = (const float*)d_in[6];
    const float* pb3 = (const float*)d_in[7];
    const float* rw1 = (const float*)d_in[8];
    const float* rb1 = (const float*)d_in[9];
    const float* rw2 = (const float*)d_in[10];
    const float* rb2 = (const float*)d_in[11];
    const float* rw3 = (const float*)d_in[12];
    const float* rb3 = (const float*)d_in[13];
    const float* w1  = (const float*)d_in[14];
    const float* b1  = (const float*)d_in[15];
    const float* w2  = (const float*)d_in[16];
    const float* b2  = (const float*)d_in[17];
    const float* w3  = (const float*)d_in[18];
    const float* b3  = (const float*)d_in[19];
    float* out = (float*)d_out;

    int n = in_sizes[0] / 64;      // 400000 rows
    int ntiles = n >> 7;           // 3125 (128-row tiles, exact)

    char* ws = (char*)d_ws;
    float* gsum = (float*)ws;                       // 256 f32 (1KB)
    _Float16* w1f = (_Float16*)(ws + 1024);         // 16384 f16 (32KB)
    _Float16* w2f = (_Float16*)(ws + 1024 + 32768); // 65536 f16 (128KB)

    prep_kernel<<<160, 512, 0, stream>>>(pw1, pw2, w1f, w2f, gsum,
                                         pw3, rw1, rw2, rw3, w1, w2, w3);
    phi_kernel<<<NBLK, 512, 0, stream>>>(x, pb1, pb2, w1f, w2f, gsum, ntiles);
    tail_kernel<<<1, 1024, 0, stream>>>(gsum, xst, pw3, pb3, rw1, rb1, rw2, rb2,
                                        rw3, rb3, w1, b1, w2, b2, w3, b3, out, (float)n);
}

// Round 15
// 129.050 us; speedup vs baseline: 1.4747x; 1.4747x over previous
//
#include <hip/hip_runtime.h>

// DeepSets fused kernel for MI355X (gfx950) — round 15.
// r14: 128-row tile spilled again (pf[4]=16 regs; VGPR capped 128, 21MB scratch).
// Register wall is final: phi stays r12-exact (proven 86us, 112 VGPR).
// r15 attacks the 38.7us non-phi overhead: prep_kernel ELIMINATED —
// (a) weight fragments converted inline in phi's prologue (one-time, 160
// L2-resident scalar loads/thread, prep's validated indexing inlined);
// (b) gsum zeroed via hipMemsetAsync (graph-legal). 2 kernels instead of 3.

typedef unsigned short u16;
typedef _Float16 f16x8 __attribute__((ext_vector_type(8)));
typedef float f32x4 __attribute__((ext_vector_type(4)));
typedef int i32x4 __attribute__((ext_vector_type(4)));

#define NBLK 256

__device__ __forceinline__ void pin_reg(f16x8& v) {
    i32x4 t = __builtin_bit_cast(i32x4, v);
    asm volatile("" : "+v"(t));
    v = __builtin_bit_cast(f16x8, t);
}
__device__ __forceinline__ unsigned pk(float a, float b) {
    return __builtin_bit_cast(unsigned, __builtin_amdgcn_cvt_pkrtz(a, b));
}

// ---------------- fused phi + pool (persistent) ------------------------------
// 8 waves; wave w owns cols [32w, 32w+32); dbuf xs + dbuf h1s, ONE barrier/iter.
// Weight fragment (validated r1-r12): elem j of (ct,ks) = W[32ks+8fg+j][16ctg+fr],
// used as MFMA A operand: D = W^T X^T = (XW)^T. Converted fp32->fp16 inline.
__global__ __attribute__((amdgpu_flat_work_group_size(512, 512), amdgpu_waves_per_eu(2, 2)))
void phi_kernel(
    const float* __restrict__ x,
    const float* __restrict__ pb1, const float* __restrict__ pb2,
    const float* __restrict__ pw1, const float* __restrict__ pw2,
    float* __restrict__ gsum, int ntiles) {
    __shared__ __align__(16) u16 xs[2][64 * 64];    // x tile fp16, swz ^((row&7)<<4)
    __shared__ __align__(16) u16 h1s[2][64 * 256];  // h1 tile fp16, swz ^((row&15)<<4)

    const int tid = threadIdx.x;
    const int l = tid & 63;
    const int w = tid >> 6;
    const int fr = l & 15;
    const int fg = l >> 4;
    const int wb = w * 32;

    // ---- inline weight conversion into registers (loop-invariant, pinned)
    f16x8 w1r[2][2];   // [ct][ks]
#pragma unroll
    for (int ct = 0; ct < 2; ++ct)
#pragma unroll
        for (int ks = 0; ks < 2; ++ks) {
            int col = 16 * (2 * w + ct) + fr;
            f16x8 f;
#pragma unroll
            for (int j = 0; j < 8; ++j)
                f[j] = (_Float16)pw1[(32 * ks + 8 * fg + j) * 256 + col];
            w1r[ct][ks] = f;
        }
    f16x8 w2r[2][8];   // [ct][ks]
#pragma unroll
    for (int ct = 0; ct < 2; ++ct)
#pragma unroll
        for (int ks = 0; ks < 8; ++ks) {
            int col = 16 * (2 * w + ct) + fr;
            f16x8 f;
#pragma unroll
            for (int j = 0; j < 8; ++j)
                f[j] = (_Float16)pw2[(32 * ks + 8 * fg + j) * 256 + col];
            w2r[ct][ks] = f;
        }
#pragma unroll
    for (int ct = 0; ct < 2; ++ct) {
#pragma unroll
        for (int ks = 0; ks < 2; ++ks) pin_reg(w1r[ct][ks]);
#pragma unroll
        for (int ks = 0; ks < 8; ++ks) pin_reg(w2r[ct][ks]);
    }
    f32x4 b1v[2], b2v[2];
#pragma unroll
    for (int ct = 0; ct < 2; ++ct) {
        int c0 = wb + ct * 16 + fg * 4;
        b1v[ct] = *(const f32x4*)(pb1 + c0);
        b2v[ct] = *(const f32x4*)(pb2 + c0);
    }

    float psum[2][4] = {{0.f, 0.f, 0.f, 0.f}, {0.f, 0.f, 0.f, 0.f}};

    const int t0 = blockIdx.x;
    // ---- prologue: stage tile t0 into xs[0], prefetch t0+NBLK into regs
    {
        const float4* xg = (const float4*)(x + (size_t)t0 * 4096);
#pragma unroll
        for (int i = 0; i < 2; ++i) {
            int f4 = tid + i * 512;
            float4 v = xg[f4];
            int row = f4 >> 4, c4 = f4 & 15;
            uint2 o;
            o.x = pk(v.x, v.y);
            o.y = pk(v.z, v.w);
            int byte = (row * 128 + c4 * 8) ^ ((row & 7) << 4);
            *(uint2*)((char*)xs[0] + byte) = o;
        }
    }
    float4 pf0, pf1;
    {
        int tn = (t0 + NBLK < ntiles) ? t0 + NBLK : 0;
        const float4* xg = (const float4*)(x + (size_t)tn * 4096);
        pf0 = xg[tid];
        pf1 = xg[tid + 512];
    }
    __syncthreads();

    int buf = 0, hb = 0;
    for (int t = t0; t < ntiles; t += NBLK) {
        // ---- stage next x tile FIRST (consume pf regs -> xs[buf^1])
#pragma unroll
        for (int i = 0; i < 2; ++i) {
            float4 v = i ? pf1 : pf0;
            int f4 = tid + i * 512;
            int row = f4 >> 4, c4 = f4 & 15;
            uint2 o;
            o.x = pk(v.x, v.y);
            o.y = pk(v.z, v.w);
            int byte = (row * 128 + c4 * 8) ^ ((row & 7) << 4);
            *(uint2*)((char*)xs[buf ^ 1] + byte) = o;
        }
        // ---- ISSUE global loads for t+2*NBLK now: they have all of GEMM1 to land
        {
            int tn = (t + 2 * NBLK < ntiles) ? t + 2 * NBLK : 0;
            const float4* xg = (const float4*)(x + (size_t)tn * 4096);
            pf0 = xg[tid];
            pf1 = xg[tid + 512];
        }

        // ---- GEMM1: D1 = (x@pw1)^T from xs[buf] -> h1s[hb]
        {
            f32x4 acc[2][4] = {};
#pragma unroll
            for (int ks = 0; ks < 2; ++ks) {
                f16x8 bd[4];
#pragma unroll
                for (int rt = 0; rt < 4; ++rt) {
                    int row = (rt << 4) + fr;
                    int byte = ((row << 7) + (ks << 6) + (fg << 4)) ^ ((row & 7) << 4);
                    bd[rt] = *(const f16x8*)((char*)xs[buf] + byte);
                }
#pragma unroll
                for (int ct = 0; ct < 2; ++ct)
#pragma unroll
                    for (int rt = 0; rt < 4; ++rt)
                        acc[ct][rt] = __builtin_amdgcn_mfma_f32_16x16x32_f16(w1r[ct][ks], bd[rt], acc[ct][rt], 0, 0, 0);
            }
            // epilogue: bias+relu, packed cvt; lane holds h-cols c0..c0+3 of row rown
#pragma unroll
            for (int ct = 0; ct < 2; ++ct) {
                int c0 = wb + ct * 16 + fg * 4;
#pragma unroll
                for (int rt = 0; rt < 4; ++rt) {
                    int rown = (rt << 4) + fr;
                    uint2 o;
                    o.x = pk(fmaxf(acc[ct][rt][0] + b1v[ct][0], 0.f),
                             fmaxf(acc[ct][rt][1] + b1v[ct][1], 0.f));
                    o.y = pk(fmaxf(acc[ct][rt][2] + b1v[ct][2], 0.f),
                             fmaxf(acc[ct][rt][3] + b1v[ct][3], 0.f));
                    int byte = ((rown << 9) + (c0 << 1)) ^ ((rown & 15) << 4);
                    *(uint2*)((char*)h1s[hb] + byte) = o;
                }
            }
        }
        __syncthreads();   // h1s[hb] + xs[buf^1] visible; prefetch loads landed

        // ---- GEMM2: D2 = (h1@pw2)^T, pool into psum
        {
            f32x4 acc2[2][4] = {};
#pragma unroll
            for (int ks = 0; ks < 8; ++ks) {
                f16x8 bd[4];
#pragma unroll
                for (int rt = 0; rt < 4; ++rt) {
                    int row = (rt << 4) + fr;
                    int byte = ((row << 9) + (ks << 6) + (fg << 4)) ^ ((row & 15) << 4);
                    bd[rt] = *(const f16x8*)((char*)h1s[hb] + byte);
                }
#pragma unroll
                for (int ct = 0; ct < 2; ++ct)
#pragma unroll
                    for (int rt = 0; rt < 4; ++rt)
                        acc2[ct][rt] = __builtin_amdgcn_mfma_f32_16x16x32_f16(w2r[ct][ks], bd[rt], acc2[ct][rt], 0, 0, 0);
            }
#pragma unroll
            for (int ct = 0; ct < 2; ++ct)
#pragma unroll
                for (int r = 0; r < 4; ++r) {
                    float v = 0.f;
#pragma unroll
                    for (int rt = 0; rt < 4; ++rt)
                        v += fmaxf(acc2[ct][rt][r] + b2v[ct][r], 0.f);
                    psum[ct][r] += v;
                }
        }
        buf ^= 1;
        hb ^= 1;
    }

    // ---- final: reduce psum over the 16 fr-lanes, one atomicAdd per col
#pragma unroll
    for (int ct = 0; ct < 2; ++ct)
#pragma unroll
        for (int r = 0; r < 4; ++r) {
            float v = psum[ct][r];
            v += __shfl_xor(v, 1, 64);
            v += __shfl_xor(v, 2, 64);
            v += __shfl_xor(v, 4, 64);
            v += __shfl_xor(v, 8, 64);
            if (fr == 0) atomicAdd(&gsum[wb + ct * 16 + fg * 4 + r], v);
        }
}

// ---------------- tail: split-K parallel rho + head (fp32, 1024 threads) ----
__global__ __launch_bounds__(1024) void tail_kernel(
    const float* __restrict__ gsum, const float* __restrict__ xst,
    const float* __restrict__ pw3, const float* __restrict__ pb3,
    const float* __restrict__ rw1, const float* __restrict__ rb1,
    const float* __restrict__ rw2, const float* __restrict__ rb2,
    const float* __restrict__ rw3, const float* __restrict__ rb3,
    const float* __restrict__ w1, const float* __restrict__ b1,
    const float* __restrict__ w2, const float* __restrict__ b2,
    const float* __restrict__ w3, const float* __restrict__ b3,
    float* __restrict__ out, float nf) {
    __shared__ float fp[128], r1[256], r2[256], tc[144], t1[256], t2[256];
    __shared__ float part[8][256];
    const int t = threadIdx.x;

    {   // fp = nf*pb3 + gsum @ pw3  (256->128, 8-way)
        int j = t & 127, q = t >> 7;
        float s = 0.f;
        for (int i = 32 * q; i < 32 * q + 32; ++i) s += gsum[i] * pw3[i * 128 + j];
        part[q][j] = s;
    }
    __syncthreads();
    if (t < 128) { float s = nf * pb3[t]; for (int q = 0; q < 8; ++q) s += part[q][t]; fp[t] = s; }
    __syncthreads();
    {   // r1 = relu(fp @ rw1 + rb1)  (128->256, 4-way)
        int j = t & 255, q = t >> 8;
        float s = 0.f;
        for (int i = 32 * q; i < 32 * q + 32; ++i) s += fp[i] * rw1[i * 256 + j];
        part[q][j] = s;
    }
    __syncthreads();
    if (t < 256) { float s = rb1[t]; for (int q = 0; q < 4; ++q) s += part[q][t]; r1[t] = fmaxf(s, 0.f); }
    __syncthreads();
    {   // r2 = relu(r1 @ rw2 + rb2)  (256->256, 4-way)
        int j = t & 255, q = t >> 8;
        float s = 0.f;
        for (int i = 64 * q; i < 64 * q + 64; ++i) s += r1[i] * rw2[i * 256 + j];
        part[q][j] = s;
    }
    __syncthreads();
    if (t < 256) { float s = rb2[t]; for (int q = 0; q < 4; ++q) s += part[q][t]; r2[t] = fmaxf(s, 0.f); }
    __syncthreads();
    {   // tc[0:128] = r2 @ rw3 + rb3  (256->128, 8-way)
        int j = t & 127, q = t >> 7;
        float s = 0.f;
        for (int i = 32 * q; i < 32 * q + 32; ++i) s += r2[i] * rw3[i * 128 + j];
        part[q][j] = s;
    }
    __syncthreads();
    if (t < 128) { float s = rb3[t]; for (int q = 0; q < 8; ++q) s += part[q][t]; tc[t] = s; }
    else if (t < 144) tc[t] = xst[t - 128];
    __syncthreads();
    {   // t1 = relu(tc @ w1 + b1)  (144->256, 4-way, 36 each)
        int j = t & 255, q = t >> 8;
        float s = 0.f;
        for (int i = 36 * q; i < 36 * q + 36; ++i) s += tc[i] * w1[i * 256 + j];
        part[q][j] = s;
    }
    __syncthreads();
    if (t < 256) { float s = b1[t]; for (int q = 0; q < 4; ++q) s += part[q][t]; t1[t] = fmaxf(s, 0.f); }
    __syncthreads();
    {   // t2 = relu(t1 @ w2 + b2)  (256->256, 4-way)
        int j = t & 255, q = t >> 8;
        float s = 0.f;
        for (int i = 64 * q; i < 64 * q + 64; ++i) s += t1[i] * w2[i * 256 + j];
        part[q][j] = s;
    }
    __syncthreads();
    if (t < 256) { float s = b2[t]; for (int q = 0; q < 4; ++q) s += part[q][t]; t2[t] = fmaxf(s, 0.f); }
    __syncthreads();
    {   // out = t2 @ w3 + b3  (256->5, 4-way)
        int j = t & 255, q = t >> 8;
        if (j < 5) {
            float s = 0.f;
            for (int i = 64 * q; i < 64 * q + 64; ++i) s += t2[i] * w3[i * 5 + j];
            part[q][j] = s;
        }
    }
    __syncthreads();
    if (t < 5) { float s = b3[t]; for (int q = 0; q < 4; ++q) s += part[q][t]; out[t] = s; }
}

extern "C" void kernel_launch(void* const* d_in, const int* in_sizes, int n_in,
                              void* d_out, int out_size, void* d_ws, size_t ws_size,
                              hipStream_t stream) {
    (void)n_in; (void)out_size; (void)ws_size;
    const float* x   = (const float*)d_in[0];
    const float* xst = (const float*)d_in[1];
    const float* pw1 = (const float*)d_in[2];
    const float* pb1 = (const float*)d_in[3];
    const float* pw2 = (const float*)d_in[4];
    const float* pb2 = (const float*)d_in[5];
    const float* pw3 = (const float*)d_in[6];
    const float* pb3 = (const float*)d_in[7];
    const float* rw1 = (const float*)d_in[8];
    const float* rb1 = (const float*)d_in[9];
    const float* rw2 = (const float*)d_in[10];
    const float* rb2 = (const float*)d_in[11];
    const float* rw3 = (const float*)d_in[12];
    const float* rb3 = (const float*)d_in[13];
    const float* w1  = (const float*)d_in[14];
    const float* b1  = (const float*)d_in[15];
    const float* w2  = (const float*)d_in[16];
    const float* b2  = (const float*)d_in[17];
    const float* w3  = (const float*)d_in[18];
    const float* b3  = (const float*)d_in[19];
    float* out = (float*)d_out;

    int n = in_sizes[0] / 64;      // 400000
    int ntiles = n >> 6;           // 6250

    float* gsum = (float*)d_ws;    // 256 f32 (1KB)
    hipMemsetAsync(gsum, 0, 256 * sizeof(float), stream);
    phi_kernel<<<NBLK, 512, 0, stream>>>(x, pb1, pb2, pw1, pw2, gsum, ntiles);
    tail_kernel<<<1, 1024, 0, stream>>>(gsum, xst, pw3, pb3, rw1, rb1, rw2, rb2,
                                        rw3, rb3, w1, b1, w2, b2, w3, b3, out, (float)n);
}